// Round 2
// baseline (424.227 us; speedup 1.0000x reference)
//
#include <hip/hip_runtime.h>

#define M_DIM 256
#define N_DIM 8192
#define K_DIM 8192
#define BN 128
#define BK 32
#define KSPLIT 4
#define KLEN (K_DIM / KSPLIT)   // 2048
#define NT (KLEN / BK)          // 64

typedef _Float16 half_t;
typedef __attribute__((ext_vector_type(8))) _Float16 half8;
typedef __attribute__((ext_vector_type(4))) float f32x4;
typedef __attribute__((ext_vector_type(4))) unsigned int u32x4;

__device__ __forceinline__ unsigned int pk2(float a, float b) {
  // v_cvt_pkrtz_f16_f32: exact for ints |v|<=2048; RTZ on x is fine vs threshold
  return __builtin_bit_cast(unsigned int, __builtin_amdgcn_cvt_pkrtz(a, b));
}

// out[m][n] += scale * sum_k x[m][k] * W[n][k]   (+ bias on ks==0)
// A (x) and B (W) both reg-staged -> cvt f16 -> LDS; compiler manages vm waits.
__global__ __launch_bounds__(512, 2) void qgemm(
    const float* __restrict__ x, const int* __restrict__ Wq,
    const float* __restrict__ scales, const float* __restrict__ bias,
    float* __restrict__ out) {
  // buf p at p*24576: A f16 [256 rows][64B] = 16K, then B f16 [128][64B] = 8K
  __shared__ __align__(1024) char lds[49152];

  const int tid = threadIdx.x;
  const int bid = blockIdx.x;
  const int p = bid & 7;              // XCD (default round-robin)
  const int g = bid >> 3;             // 0..31
  const int ks = p >> 1;              // k-split 0..3: one x-quarter per XCD (L2 reuse)
  const int t = (g << 1) | (p & 1);   // N-tile 0..63
  const int col0 = t * BN;
  const int kbase = ks * KLEN;

  const int wid = tid >> 6, lane = tid & 63;
  const int wm = wid >> 1, wn = wid & 1;       // 4x2 waves, wave tile 64x64
  const int r16 = lane & 15, g4 = lane >> 4;

  // staging roles
  const int xr = tid >> 1, xh2 = tid & 1;      // x: row 0..255, which 16-f32 half
  const int wr = tid >> 2, wc = tid & 3;       // W: row 0..127, which 8-int chunk

  const float* xp = x + (size_t)xr * K_DIM + kbase + xh2 * 16;
  const int* wp = Wq + (size_t)(col0 + wr) * K_DIM + kbase + wc * 8;

  // LDS write offsets (XOR chunk swizzle by (row>>1)&3 -> 2-way reads, free)
  const int sA = (xr >> 1) & 3;
  const int aw0 = xr * 64 + (((xh2 * 2 + 0) ^ sA) << 4);
  const int aw1 = xr * 64 + (((xh2 * 2 + 1) ^ sA) << 4);
  const int sB = (wr >> 1) & 3;
  const int bw0 = 16384 + wr * 64 + ((wc ^ sB) << 4);

  // fragment read offsets (within a buffer)
  int aoff[4], boff[4];
#pragma unroll
  for (int mf = 0; mf < 4; ++mf) {
    int ra = wm * 64 + mf * 16 + r16;
    aoff[mf] = ra * 64 + ((g4 ^ ((ra >> 1) & 3)) << 4);
  }
#pragma unroll
  for (int nf = 0; nf < 4; ++nf) {
    int rb = wn * 64 + nf * 16 + r16;
    boff[nf] = 16384 + rb * 64 + ((g4 ^ ((rb >> 1) & 3)) << 4);
  }

  f32x4 acc[4][4];
#pragma unroll
  for (int i = 0; i < 4; ++i)
#pragma unroll
    for (int j = 0; j < 4; ++j) acc[i][j] = (f32x4){0.f, 0.f, 0.f, 0.f};

  // prologue loads for kt=0
  float4 X0 = *(const float4*)(xp);
  float4 X1 = *(const float4*)(xp + 4);
  float4 X2 = *(const float4*)(xp + 8);
  float4 X3 = *(const float4*)(xp + 12);
  int4 Wa = *(const int4*)(wp);
  int4 Wb = *(const int4*)(wp + 4);

  for (int kt = 0; kt < NT; ++kt) {
    char* B0 = lds + (kt & 1) * 24576;

    // ---- stage buf[kt&1] from regs ----
    u32x4 pa0, pa1, pb;
    pa0.x = pk2(X0.x, X0.y); pa0.y = pk2(X0.z, X0.w);
    pa0.z = pk2(X1.x, X1.y); pa0.w = pk2(X1.z, X1.w);
    pa1.x = pk2(X2.x, X2.y); pa1.y = pk2(X2.z, X2.w);
    pa1.z = pk2(X3.x, X3.y); pa1.w = pk2(X3.z, X3.w);
    pb.x = pk2((float)Wa.x, (float)Wa.y); pb.y = pk2((float)Wa.z, (float)Wa.w);
    pb.z = pk2((float)Wb.x, (float)Wb.y); pb.w = pk2((float)Wb.z, (float)Wb.w);
    *(u32x4*)(B0 + aw0) = pa0;
    *(u32x4*)(B0 + aw1) = pa1;
    *(u32x4*)(B0 + bw0) = pb;

    // ---- prefetch next K-step (flies across the MFMA phase) ----
    if (kt + 1 < NT) {
      xp += BK; wp += BK;
      X0 = *(const float4*)(xp);
      X1 = *(const float4*)(xp + 4);
      X2 = *(const float4*)(xp + 8);
      X3 = *(const float4*)(xp + 12);
      Wa = *(const int4*)(wp);
      Wb = *(const int4*)(wp + 4);
    }

    asm volatile("s_waitcnt lgkmcnt(0)" ::: "memory");
    __builtin_amdgcn_s_barrier();
    __builtin_amdgcn_sched_barrier(0);

    // ---- compute on buf[kt&1] ----
    half8 af[4], bf[4];
#pragma unroll
    for (int mf = 0; mf < 4; ++mf) af[mf] = *(const half8*)(B0 + aoff[mf]);
#pragma unroll
    for (int nf = 0; nf < 4; ++nf) bf[nf] = *(const half8*)(B0 + boff[nf]);
#pragma unroll
    for (int mf = 0; mf < 4; ++mf)
#pragma unroll
      for (int nf = 0; nf < 4; ++nf)
        acc[mf][nf] = __builtin_amdgcn_mfma_f32_16x16x32_f16(
            af[mf], bf[nf], acc[mf][nf], 0, 0, 0);
    // single barrier per iter is safe: next stage writes the OTHER buffer, and a
    // wave reaching barrier(kt+1) has necessarily finished compute(kt)'s reads.
  }

  // ---- epilogue: scale, bias (ks==0 only), atomic k-split accumulate ----
  const float scale = scales[0];
#pragma unroll
  for (int nf = 0; nf < 4; ++nf) {
    const int gcol = col0 + wn * 64 + nf * 16 + r16;
    const float bv = (ks == 0) ? bias[gcol] : 0.0f;
#pragma unroll
    for (int mf = 0; mf < 4; ++mf) {
      const int grow0 = wm * 64 + mf * 16 + g4 * 4;
#pragma unroll
      for (int j = 0; j < 4; ++j) {
        atomicAdd(out + (size_t)(grow0 + j) * N_DIM + gcol,
                  scale * acc[mf][nf][j] + bv);
      }
    }
  }
}

extern "C" void kernel_launch(void* const* d_in, const int* in_sizes, int n_in,
                              void* d_out, int out_size, void* d_ws, size_t ws_size,
                              hipStream_t stream) {
  const float* x = (const float*)d_in[0];
  const int* Wq = (const int*)d_in[1];        // int8 widened to int32 by harness
  const float* scales = (const float*)d_in[2];
  const float* bias = (const float*)d_in[3];
  float* out = (float*)d_out;

  hipMemsetAsync(d_out, 0, (size_t)M_DIM * N_DIM * sizeof(float), stream);
  qgemm<<<dim3(256), dim3(512), 0, stream>>>(x, Wq, scales, bias, out);
}

// Round 3
// 423.290 us; speedup vs baseline: 1.0022x; 1.0022x over previous
//
#include <hip/hip_runtime.h>

#define M_DIM 256
#define N_DIM 8192
#define K_DIM 8192
#define BN 128
#define BK 32
#define KSPLIT 4
#define KLEN (K_DIM / KSPLIT)   // 2048
#define NT (KLEN / BK)          // 64
#define ABYTES 16384            // A tile: 256 rows x 32 k x f16
#define BBYTES 8192             // B tile: 128 rows x 32 k x f16
#define BUFB (ABYTES + BBYTES)  // 24576 per buffer

typedef _Float16 half_t;
typedef __attribute__((ext_vector_type(8))) _Float16 half8;
typedef __attribute__((ext_vector_type(4))) float f32x4;
typedef __attribute__((ext_vector_type(4))) unsigned int u32x4;

__device__ __forceinline__ unsigned int pk2(float a, float b) {
  // exact for integers |v| <= 2048 (W path); x already rounded in convert_x
  return __builtin_bit_cast(unsigned int, __builtin_amdgcn_cvt_pkrtz(a, b));
}
__device__ __forceinline__ void gl16(const void* g, void* l) {
  __builtin_amdgcn_global_load_lds(
      (const __attribute__((address_space(1))) unsigned int*)g,
      (__attribute__((address_space(3))) unsigned int*)l, 16, 0, 0);
}

// ---- x f32 [256][8192] -> f16 K-tiled [256 kt][256 row][32 kk] (RNE) ----
__global__ __launch_bounds__(256) void convert_x(const float* __restrict__ x,
                                                 half_t* __restrict__ xh) {
  const int gid = blockIdx.x * 256 + threadIdx.x;  // 262144 threads
  const int row = gid >> 10;
  const int k0 = (gid & 1023) << 3;
  float4 v0 = *(const float4*)(x + (size_t)row * K_DIM + k0);
  float4 v1 = *(const float4*)(x + (size_t)row * K_DIM + k0 + 4);
  half8 h;
  h[0] = (half_t)v0.x; h[1] = (half_t)v0.y; h[2] = (half_t)v0.z; h[3] = (half_t)v0.w;
  h[4] = (half_t)v1.x; h[5] = (half_t)v1.y; h[6] = (half_t)v1.z; h[7] = (half_t)v1.w;
  const int kt = k0 >> 5, kk = k0 & 31;
  *(half8*)(xh + (size_t)kt * 8192 + row * 32 + kk) = h;
}

// ---- out[m][n] += scale * sum_k x[m][k]*W[n][k]  (+bias on ks==0) ----
__global__ __launch_bounds__(512, 2) void qgemm(
    const half_t* __restrict__ xh, const int* __restrict__ Wq,
    const float* __restrict__ scales, const float* __restrict__ bias,
    float* __restrict__ out) {
  __shared__ __align__(1024) char lds[2 * BUFB];  // 48 KB

  const int tid = threadIdx.x;
  const int bid = blockIdx.x;
  const int p = bid & 7;             // XCD (round-robin dispatch)
  const int g = bid >> 3;
  const int ks = p >> 1;             // k-quarter: 2 XCDs each -> 1MB x-slice L2-res
  const int t = (g << 1) | (p & 1);  // N-tile 0..63
  const int col0 = t * BN;

  const int wid = tid >> 6, lane = tid & 63;
  const int wm = wid >> 1, wn = wid & 1;       // 4x2 waves, wave tile 64x64
  const int r16 = lane & 15, g4 = lane >> 4;

  // A source: K-tiled xh; this block's quarter starts at tile ks*NT
  const half_t* abase = xh + (size_t)(ks * NT) * 8192;
  // W source: thread (wr, wc) stages 8 int32 (32B) per tile
  const int wr = tid >> 2, wc = tid & 3;
  const int* wp0 = Wq + (size_t)(col0 + wr) * K_DIM + ks * KLEN + wc * 8;
  const int wlds = ABYTES + wr * 64 + wc * 16;

  // fragment read offsets (linear layouts are bank-uniform; no swizzle needed)
  int aoff[4], boff[4];
#pragma unroll
  for (int mf = 0; mf < 4; ++mf) aoff[mf] = (wm * 64 + mf * 16 + r16) * 64 + g4 * 16;
#pragma unroll
  for (int nf = 0; nf < 4; ++nf) boff[nf] = ABYTES + (wn * 64 + nf * 16 + r16) * 64 + g4 * 16;

  f32x4 acc[4][4];
#pragma unroll
  for (int i = 0; i < 4; ++i)
#pragma unroll
    for (int j = 0; j < 4; ++j) acc[i][j] = (f32x4){0.f, 0.f, 0.f, 0.f};

  int4 Wa, Wb;  // W regs for the NEXT tile's ds_write
  // ---- prologue: stage tile 0 into buf 0, preload W tile 1 ----
  {
    int4 w0a = *(const int4*)(wp0);
    int4 w0b = *(const int4*)(wp0 + 4);
    gl16(abase + tid * 8, lds + tid * 16);
    gl16(abase + 4096 + tid * 8, lds + 8192 + tid * 16);
    __builtin_amdgcn_sched_barrier(0);
    u32x4 pb;
    pb.x = pk2((float)w0a.x, (float)w0a.y); pb.y = pk2((float)w0a.z, (float)w0a.w);
    pb.z = pk2((float)w0b.x, (float)w0b.y); pb.w = pk2((float)w0b.z, (float)w0b.w);
    *(u32x4*)(lds + wlds) = pb;
    Wa = *(const int4*)(wp0 + 32);
    Wb = *(const int4*)(wp0 + 36);
    __builtin_amdgcn_sched_barrier(0);
    asm volatile("s_waitcnt vmcnt(2) lgkmcnt(0)" ::: "memory");  // gl16s done; W1 flies
    __builtin_amdgcn_s_barrier();
  }

  for (int kt = 0; kt < NT; ++kt) {
    char* Bc = lds + (kt & 1) * BUFB;
    char* Bn = lds + ((kt & 1) ^ 1) * BUFB;

    // 1. ds_write W(kt+1) from regs into the freed buffer
    u32x4 pb;
    pb.x = pk2((float)Wa.x, (float)Wa.y); pb.y = pk2((float)Wa.z, (float)Wa.w);
    pb.z = pk2((float)Wb.x, (float)Wb.y); pb.w = pk2((float)Wb.z, (float)Wb.w);
    *(u32x4*)(Bn + wlds) = pb;

    // 2. async A(kt+1) -> LDS (clamped on last iter; buffer unread then)
    const int an = (kt + 1 < NT) ? kt + 1 : NT - 1;
    const half_t* asrc = abase + (size_t)an * 8192;
    gl16(asrc + tid * 8, Bn + tid * 16);
    gl16(asrc + 4096 + tid * 8, Bn + 8192 + tid * 16);
    __builtin_amdgcn_sched_barrier(0);

    // 3. W loads for kt+2 (counted, stay in flight across the barrier)
    const int w2 = (kt + 2 < NT) ? kt + 2 : NT - 1;
    Wa = *(const int4*)(wp0 + (size_t)w2 * 32);
    Wb = *(const int4*)(wp0 + (size_t)w2 * 32 + 4);

    // 4. compute on current buffer
    half8 af[4], bf[4];
#pragma unroll
    for (int mf = 0; mf < 4; ++mf) af[mf] = *(const half8*)(Bc + aoff[mf]);
#pragma unroll
    for (int nf = 0; nf < 4; ++nf) bf[nf] = *(const half8*)(Bc + boff[nf]);
#pragma unroll
    for (int mf = 0; mf < 4; ++mf)
#pragma unroll
      for (int nf = 0; nf < 4; ++nf)
        acc[mf][nf] = __builtin_amdgcn_mfma_f32_16x16x32_f16(
            af[mf], bf[nf], acc[mf][nf], 0, 0, 0);

    // 5. counted wait: gl16s complete; the 2 newer W loads keep flying
    __builtin_amdgcn_sched_barrier(0);
    asm volatile("s_waitcnt vmcnt(2) lgkmcnt(0)" ::: "memory");
    __builtin_amdgcn_s_barrier();
  }

  // ---- epilogue: scale, bias (ks==0), atomic k-split accumulate ----
  const float scale = scales[0];
#pragma unroll
  for (int nf = 0; nf < 4; ++nf) {
    const int gcol = col0 + wn * 64 + nf * 16 + r16;
    const float bv = (ks == 0) ? bias[gcol] : 0.0f;
#pragma unroll
    for (int mf = 0; mf < 4; ++mf) {
      const int grow0 = wm * 64 + mf * 16 + g4 * 4;
#pragma unroll
      for (int j = 0; j < 4; ++j) {
        atomicAdd(out + (size_t)(grow0 + j) * N_DIM + gcol,
                  scale * acc[mf][nf][j] + bv);
      }
    }
  }
}

extern "C" void kernel_launch(void* const* d_in, const int* in_sizes, int n_in,
                              void* d_out, int out_size, void* d_ws, size_t ws_size,
                              hipStream_t stream) {
  const float* x = (const float*)d_in[0];
  const int* Wq = (const int*)d_in[1];  // int8 weights widened to int32
  const float* scales = (const float*)d_in[2];
  const float* bias = (const float*)d_in[3];
  float* out = (float*)d_out;
  half_t* xh = (half_t*)d_ws;  // 4 MB K-tiled f16 x

  hipMemsetAsync(d_out, 0, (size_t)M_DIM * N_DIM * sizeof(float), stream);
  convert_x<<<dim3(1024), dim3(256), 0, stream>>>(x, xh);
  qgemm<<<dim3(256), dim3(512), 0, stream>>>(xh, Wq, scales, bias, out);
}

// Round 5
// 408.631 us; speedup vs baseline: 1.0382x; 1.0359x over previous
//
#include <hip/hip_runtime.h>

#define M_DIM 256
#define N_DIM 8192
#define K_DIM 8192
#define BN 64
#define BK 32
#define KSPLIT 4
#define KLEN (K_DIM / KSPLIT)   // 2048
#define NT (KLEN / BK)          // 64
#define ABY 16384               // A tile: 256 rows x 32 k x f16
#define BBY 4096                // B tile: 64 rows x 32 k x f16
#define BUFB (ABY + BBY)        // 20480 per buffer, x4 = 80 KB

typedef _Float16 half_t;
typedef __attribute__((ext_vector_type(8))) _Float16 half8;
typedef __attribute__((ext_vector_type(4))) float f32x4;
typedef __attribute__((ext_vector_type(2))) unsigned int u32x2;

__device__ __forceinline__ unsigned int pk2(float a, float b) {
  // exact for integers |v| <= 2048 (W path); x already RNE-rounded in convert_x
  return __builtin_bit_cast(unsigned int, __builtin_amdgcn_cvt_pkrtz(a, b));
}
__device__ __forceinline__ void gl16(const void* g, void* l) {
  __builtin_amdgcn_global_load_lds(
      (const __attribute__((address_space(1))) unsigned int*)g,
      (__attribute__((address_space(3))) unsigned int*)l, 16, 0, 0);
}

// ---- x f32 [256][8192] -> f16, K-tiled [kt][row][32], chunk-XOR-swizzled ----
// 16B chunk c of (row, kt) stored at position c ^ ((row>>1)&3)  (rule 21:
// swizzle baked into the SOURCE so linear global_load_lds + swizzled ds_read match)
__global__ __launch_bounds__(256) void convert_x(const float* __restrict__ x,
                                                 half_t* __restrict__ xh) {
  const int gid = blockIdx.x * 256 + threadIdx.x;  // 262144
  const int row = gid >> 10;
  const int k0 = (gid & 1023) << 3;
  float4 v0 = *(const float4*)(x + (size_t)row * K_DIM + k0);
  float4 v1 = *(const float4*)(x + (size_t)row * K_DIM + k0 + 4);
  half8 h;
  h[0] = (half_t)v0.x; h[1] = (half_t)v0.y; h[2] = (half_t)v0.z; h[3] = (half_t)v0.w;
  h[4] = (half_t)v1.x; h[5] = (half_t)v1.y; h[6] = (half_t)v1.z; h[7] = (half_t)v1.w;
  const int kt = k0 >> 5;
  const int cx = ((k0 >> 3) & 3) ^ ((row >> 1) & 3);
  *(half8*)(xh + (size_t)kt * 8192 + row * 32 + cx * 8) = h;
}

// ---- out[m][n] += scale * sum_k x[m][k]*W[n][k]  (+bias on ks==0) ----
__global__ __launch_bounds__(512, 4) void qgemm(
    const half_t* __restrict__ xh, const int* __restrict__ Wq,
    const float* __restrict__ scales, const float* __restrict__ bias,
    float* __restrict__ out) {
  __shared__ __align__(1024) char lds[4 * BUFB];  // 81920 B -> 2 blocks/CU

  const int tid = threadIdx.x;
  const int bid = blockIdx.x;
  const int p = bid & 7;             // XCD (round-robin dispatch)
  const int ks = p >> 1;             // k-quarter: 2 XCDs share a 1MB x-slice (L2)
  const int t = ((bid >> 3) << 1) | (p & 1);  // N-tile 0..127
  const int col0 = t * BN;

  const int wid = tid >> 6, lane = tid & 63;
  const int wm = wid >> 1, wn = wid & 1;       // 4x2 waves, wave tile 64x32
  const int r16 = lane & 15, g4 = lane >> 4;

  const half_t* abase = xh + (size_t)(ks * NT) * 8192;
  // W staging: thread (wr, wc) loads 1 int4 (4 weights) per tile
  const int wr = tid >> 3, wc = tid & 7;
  const int* wp0 = Wq + (size_t)(col0 + wr) * K_DIM + ks * KLEN + wc * 4;
  const int wlds = ABY + wr * 64 + (((wc >> 1) ^ ((wr >> 1) & 3)) << 4) + ((wc & 1) << 3);

  // fragment read offsets (chunk-XOR swizzle -> 2-way banks, free)
  int aoff[4], boff[2];
#pragma unroll
  for (int mf = 0; mf < 4; ++mf) {
    int ra = wm * 64 + mf * 16 + r16;
    aoff[mf] = ra * 64 + ((g4 ^ ((ra >> 1) & 3)) << 4);
  }
#pragma unroll
  for (int nf = 0; nf < 2; ++nf) {
    int rb = wn * 32 + nf * 16 + r16;
    boff[nf] = ABY + rb * 64 + ((g4 ^ ((rb >> 1) & 3)) << 4);
  }

  f32x4 acc[4][2];
#pragma unroll
  for (int i = 0; i < 4; ++i)
#pragma unroll
    for (int j = 0; j < 2; ++j) acc[i][j] = (f32x4){0.f, 0.f, 0.f, 0.f};

  int4 Wset0, Wset1, Wset2, Wset3;

  // ---- prologue: issue order L(0) G(0)x2 L(1) G(1)x2 L(2), pinned ----
  Wset0 = *(const int4*)(wp0);
  __builtin_amdgcn_sched_barrier(0);
  gl16(abase + tid * 8, lds + tid * 16);
  gl16(abase + 4096 + tid * 8, lds + 8192 + tid * 16);
  __builtin_amdgcn_sched_barrier(0);
  Wset1 = *(const int4*)(wp0 + 32);
  __builtin_amdgcn_sched_barrier(0);
  gl16(abase + 8192 + tid * 8, lds + BUFB + tid * 16);
  gl16(abase + 8192 + 4096 + tid * 8, lds + BUFB + 8192 + tid * 16);
  __builtin_amdgcn_sched_barrier(0);
  Wset2 = *(const int4*)(wp0 + 64);
  __builtin_amdgcn_sched_barrier(0);
  asm volatile("s_waitcnt vmcnt(6)" ::: "memory");  // W(0) ready
  {
    u32x2 pb;
    pb.x = pk2((float)Wset0.x, (float)Wset0.y);
    pb.y = pk2((float)Wset0.z, (float)Wset0.w);
    *(u32x2*)(lds + wlds) = pb;
  }
  __builtin_amdgcn_sched_barrier(0);
  asm volatile("s_waitcnt vmcnt(4) lgkmcnt(0)" ::: "memory");  // A(0) staged
  __builtin_amdgcn_s_barrier();
  __builtin_amdgcn_sched_barrier(0);

  // per iter KT: top wait W(KT+1)[issued KT-2]; ds_write it; gl16 A(KT+2);
  // load W(KT+3); compute buf[KT&3]; end wait A(KT+1) done; barrier.
#define ONE_ITER(KT, C0, C1, C2, C3)                                          \
  {                                                                           \
    asm volatile("s_waitcnt vmcnt(3)" ::: "memory");                          \
    __builtin_amdgcn_sched_barrier(0);                                        \
    {                                                                         \
      u32x2 pb;                                                               \
      pb.x = pk2((float)Wset##C1.x, (float)Wset##C1.y);                       \
      pb.y = pk2((float)Wset##C1.z, (float)Wset##C1.w);                       \
      *(u32x2*)(lds + (C1)*BUFB + wlds) = pb;                                 \
    }                                                                         \
    __builtin_amdgcn_sched_barrier(0);                                        \
    {                                                                         \
      const int an = ((KT) + 2 < NT) ? (KT) + 2 : NT - 1;                     \
      const half_t* asrc = abase + (size_t)an * 8192;                         \
      gl16(asrc + tid * 8, lds + (C2)*BUFB + tid * 16);                       \
      gl16(asrc + 4096 + tid * 8, lds + (C2)*BUFB + 8192 + tid * 16);         \
    }                                                                         \
    __builtin_amdgcn_sched_barrier(0);                                        \
    {                                                                         \
      const int w3 = ((KT) + 3 < NT) ? (KT) + 3 : NT - 1;                     \
      Wset##C3 = *(const int4*)(wp0 + (size_t)w3 * 32);                       \
    }                                                                         \
    __builtin_amdgcn_sched_barrier(0);                                        \
    {                                                                         \
      const char* Bc = lds + (C0)*BUFB;                                       \
      half8 af0 = *(const half8*)(Bc + aoff[0]);                              \
      half8 af1 = *(const half8*)(Bc + aoff[1]);                              \
      half8 af2 = *(const half8*)(Bc + aoff[2]);                              \
      half8 af3 = *(const half8*)(Bc + aoff[3]);                              \
      half8 bf0 = *(const half8*)(Bc + boff[0]);                              \
      half8 bf1 = *(const half8*)(Bc + boff[1]);                              \
      acc[0][0] = __builtin_amdgcn_mfma_f32_16x16x32_f16(af0, bf0, acc[0][0], 0, 0, 0); \
      acc[0][1] = __builtin_amdgcn_mfma_f32_16x16x32_f16(af0, bf1, acc[0][1], 0, 0, 0); \
      acc[1][0] = __builtin_amdgcn_mfma_f32_16x16x32_f16(af1, bf0, acc[1][0], 0, 0, 0); \
      acc[1][1] = __builtin_amdgcn_mfma_f32_16x16x32_f16(af1, bf1, acc[1][1], 0, 0, 0); \
      acc[2][0] = __builtin_amdgcn_mfma_f32_16x16x32_f16(af2, bf0, acc[2][0], 0, 0, 0); \
      acc[2][1] = __builtin_amdgcn_mfma_f32_16x16x32_f16(af2, bf1, acc[2][1], 0, 0, 0); \
      acc[3][0] = __builtin_amdgcn_mfma_f32_16x16x32_f16(af3, bf0, acc[3][0], 0, 0, 0); \
      acc[3][1] = __builtin_amdgcn_mfma_f32_16x16x32_f16(af3, bf1, acc[3][1], 0, 0, 0); \
    }                                                                         \
    __builtin_amdgcn_sched_barrier(0);                                        \
    asm volatile("s_waitcnt vmcnt(4) lgkmcnt(0)" ::: "memory");               \
    __builtin_amdgcn_s_barrier();                                             \
    __builtin_amdgcn_sched_barrier(0);                                        \
  }

  for (int kt0 = 0; kt0 < NT; kt0 += 4) {
    ONE_ITER(kt0 + 0, 0, 1, 2, 3)
    ONE_ITER(kt0 + 1, 1, 2, 3, 0)
    ONE_ITER(kt0 + 2, 2, 3, 0, 1)
    ONE_ITER(kt0 + 3, 3, 0, 1, 2)
  }
#undef ONE_ITER

  // ---- epilogue: scale, bias (ks==0), atomic k-split accumulate ----
  const float scale = scales[0];
#pragma unroll
  for (int nf = 0; nf < 2; ++nf) {
    const int gcol = col0 + wn * 32 + nf * 16 + r16;
    const float bv = (ks == 0) ? bias[gcol] : 0.0f;
#pragma unroll
    for (int mf = 0; mf < 4; ++mf) {
      const int grow0 = wm * 64 + mf * 16 + g4 * 4;
#pragma unroll
      for (int j = 0; j < 4; ++j) {
        atomicAdd(out + (size_t)(grow0 + j) * N_DIM + gcol,
                  scale * acc[mf][nf][j] + bv);
      }
    }
  }
}

extern "C" void kernel_launch(void* const* d_in, const int* in_sizes, int n_in,
                              void* d_out, int out_size, void* d_ws, size_t ws_size,
                              hipStream_t stream) {
  const float* x = (const float*)d_in[0];
  const int* Wq = (const int*)d_in[1];  // int8 weights widened to int32
  const float* scales = (const float*)d_in[2];
  const float* bias = (const float*)d_in[3];
  float* out = (float*)d_out;
  half_t* xh = (half_t*)d_ws;  // 4 MB K-tiled f16 x

  hipMemsetAsync(d_out, 0, (size_t)M_DIM * N_DIM * sizeof(float), stream);
  convert_x<<<dim3(1024), dim3(256), 0, stream>>>(x, xh);
  qgemm<<<dim3(512), dim3(512), 0, stream>>>(xh, Wq, scales, bias, out);
}